// Round 1
// baseline (105.617 us; speedup 1.0000x reference)
//
#include <hip/hip_runtime.h>

// Projector: out[n][j][k] = scale * sum_t trilinear(vol, p(t)+63.5)
//   p(t) = dc + j_c[j]*u + k_c[k]*v + t_c[t]*ray,  j_c/k_c = idx-63.5
// Constants (X=Y=Z=128):
//   n_depth = ceil(128*sqrt(3)) = 222
//   max_extent = 96*sqrt(3) = 166.2768775266122
//   dt = 2*me/221, scale = 2*me/222
constexpr int ND = 222;

__global__ __launch_bounds__(256) void projector_kernel(
    const float* __restrict__ vol,
    const float* __restrict__ vecs,
    float* __restrict__ out)
{
    const int tid = blockIdx.x * blockDim.x + threadIdx.x;
    const int k = tid & 127;
    const int j = (tid >> 7) & 127;
    const int n = tid >> 14;

    const float* vp = vecs + n * 12;
    const float rx = vp[0], ry = vp[1], rz = vp[2];
    const float dcx = vp[3], dcy = vp[4], dcz = vp[5];
    const float ux = vp[6], uy = vp[7], uz = vp[8];
    const float vx = vp[9], vy = vp[10], vz = vp[11];

    const float jc = (float)j - 63.5f;
    const float kc = (float)k - 63.5f;

    // base point in index space (grid_sample transform folded: +63.5)
    const float bx = dcx + jc * ux + kc * vx + 63.5f;
    const float by = dcy + jc * uy + kc * vy + 63.5f;
    const float bz = dcz + jc * uz + kc * vz + 63.5f;

    const float t0c = -166.2768775266122f;   // -max_extent
    const float dtc = 1.5047681223222824f;   // 2*me/221

    // ---- analytic t-window: sample can be nonzero only if every axis coord
    // lies in (-1, 128). Slab-clip t against [-1.01, 128.01] (margin; OOB
    // corners inside the window are masked to weight 0 anyway).
    float tlo = -1e30f, thi = 1e30f;
    const float bs[3] = {bx, by, bz};
    const float rs[3] = {rx, ry, rz};
    #pragma unroll
    for (int a = 0; a < 3; ++a) {
        const float b = bs[a], r = rs[a];
        if (fabsf(r) > 1e-8f) {
            const float inv = 1.0f / r;
            const float t1 = (-1.01f - b) * inv;
            const float t2 = (128.01f - b) * inv;
            tlo = fmaxf(tlo, fminf(t1, t2));
            thi = fminf(thi, fmaxf(t1, t2));
        } else if (b < -1.01f || b > 128.01f) {
            tlo = 1e30f; thi = -1e30f;   // ray never enters: empty window
        }
    }
    int tb = (int)ceilf((tlo - t0c) / dtc);   // cvt saturates on +-huge
    int te = (int)floorf((thi - t0c) / dtc);
    tb = max(tb, 0);
    te = min(te, ND - 1);

    float acc = 0.0f;
    for (int t = tb; t <= te; ++t) {
        const float tc = fmaf(dtc, (float)t, t0c);
        const float ix = fmaf(tc, rx, bx);
        const float iy = fmaf(tc, ry, by);
        const float iz = fmaf(tc, rz, bz);

        const float x0f = floorf(ix), y0f = floorf(iy), z0f = floorf(iz);
        const float fx = ix - x0f, fy = iy - y0f, fz = iz - z0f;
        const int x0 = (int)x0f, y0 = (int)y0f, z0 = (int)z0f;
        const int x1 = x0 + 1, y1 = y0 + 1, z1 = z0 + 1;

        // per-axis masked weights (zeros padding) + clamped indices
        const float wx0 = ((unsigned)x0 < 128u) ? (1.0f - fx) : 0.0f;
        const float wx1 = ((unsigned)x1 < 128u) ? fx : 0.0f;
        const float wy0 = ((unsigned)y0 < 128u) ? (1.0f - fy) : 0.0f;
        const float wy1 = ((unsigned)y1 < 128u) ? fy : 0.0f;
        const float wz0 = ((unsigned)z0 < 128u) ? (1.0f - fz) : 0.0f;
        const float wz1 = ((unsigned)z1 < 128u) ? fz : 0.0f;

        const int xa = min(max(x0, 0), 127) << 14;
        const int xb2 = min(max(x1, 0), 127) << 14;
        const int ya = min(max(y0, 0), 127) << 7;
        const int yb = min(max(y1, 0), 127) << 7;
        const int za = min(max(z0, 0), 127);
        const int zb = min(max(z1, 0), 127);

        const float v000 = vol[xa + ya + za];
        const float v001 = vol[xa + ya + zb];
        const float v010 = vol[xa + yb + za];
        const float v011 = vol[xa + yb + zb];
        const float v100 = vol[xb2 + ya + za];
        const float v101 = vol[xb2 + ya + zb];
        const float v110 = vol[xb2 + yb + za];
        const float v111 = vol[xb2 + yb + zb];

        const float w00 = wx0 * wy0, w01 = wx0 * wy1;
        const float w10 = wx1 * wy0, w11 = wx1 * wy1;
        const float s0 = w00 * v000 + w01 * v010 + w10 * v100 + w11 * v110;
        const float s1 = w00 * v001 + w01 * v011 + w10 * v101 + w11 * v111;
        acc = fmaf(s0, wz0, acc);
        acc = fmaf(s1, wz1, acc);
    }

    out[tid] = acc * 1.4979898876271372f;   // * 2*me/222
}

extern "C" void kernel_launch(void* const* d_in, const int* in_sizes, int n_in,
                              void* d_out, int out_size, void* d_ws, size_t ws_size,
                              hipStream_t stream) {
    const float* vol  = (const float*)d_in[0];   // (128,128,128) fp32
    const float* vecs = (const float*)d_in[1];   // (8,12) fp32
    float* out = (float*)d_out;                  // (8,128,128) fp32

    const int total = 8 * 128 * 128;             // == out_size
    dim3 block(256);
    dim3 grid(total / 256);
    projector_kernel<<<grid, block, 0, stream>>>(vol, vecs, out);
}

// Round 2
// 78.651 us; speedup vs baseline: 1.3428x; 1.3428x over previous
//
#include <hip/hip_runtime.h>

// Projector: out[n][j][k] = scale * sum_t trilinear(vol, p(t)+63.5)
//   p(t) = dc + j_c[j]*u + k_c[k]*v + t_c[t]*ray,  j_c/k_c = idx-63.5
// Constants (X=Y=Z=128):
//   n_depth = 222, max_extent = 96*sqrt(3), dt = 2*me/221, scale = 2*me/222
//
// R2: t-range split into 8 chunks (blockIdx.y) + atomicAdd partials -> fixes
// occupancy (512 -> 4096 blocks). z-axis is degenerate for this input
// (ray_z=u_z=dc_z=0, v=(0,0,1) => iz == k exactly, fz == 0): fast path with
// 4 loads/iter and all z math hoisted. General 8-load path kept as fallback.
constexpr int ND = 222;
constexpr int NCHUNK = 8;
constexpr int CHUNK = (ND + NCHUNK - 1) / NCHUNK;  // 28

__global__ __launch_bounds__(256) void projector_kernel(
    const float* __restrict__ vol,
    const float* __restrict__ vecs,
    float* __restrict__ out)
{
    const int tid = blockIdx.x * blockDim.x + threadIdx.x;
    const int k = tid & 127;
    const int j = (tid >> 7) & 127;
    const int n = tid >> 14;

    const float* vp = vecs + n * 12;
    const float rx = vp[0], ry = vp[1], rz = vp[2];
    const float dcx = vp[3], dcy = vp[4], dcz = vp[5];
    const float ux = vp[6], uy = vp[7], uz = vp[8];
    const float vx = vp[9], vy = vp[10], vz = vp[11];

    const float jc = (float)j - 63.5f;
    const float kc = (float)k - 63.5f;

    // base point in index space (grid_sample transform folded: +63.5)
    const float bx = dcx + jc * ux + kc * vx + 63.5f;
    const float by = dcy + jc * uy + kc * vy + 63.5f;
    const float bz = dcz + jc * uz + kc * vz + 63.5f;

    const float t0c = -166.2768775266122f;   // -max_extent
    const float dtc = 1.5047681223222824f;   // 2*me/221

    // ---- analytic t-window: nonzero sample requires every axis in (-1,128).
    float tlo = -1e30f, thi = 1e30f;
    const float bs[3] = {bx, by, bz};
    const float rs[3] = {rx, ry, rz};
    #pragma unroll
    for (int a = 0; a < 3; ++a) {
        const float b = bs[a], r = rs[a];
        if (fabsf(r) > 1e-8f) {
            const float inv = 1.0f / r;
            const float t1 = (-1.01f - b) * inv;
            const float t2 = (128.01f - b) * inv;
            tlo = fmaxf(tlo, fminf(t1, t2));
            thi = fminf(thi, fmaxf(t1, t2));
        } else if (b < -1.01f || b > 128.01f) {
            tlo = 1e30f; thi = -1e30f;   // never enters
        }
    }
    int tb = (int)ceilf((tlo - t0c) / dtc);   // cvt saturates on +-huge
    int te = (int)floorf((thi - t0c) / dtc);
    // intersect with this block's t-chunk
    const int c0 = blockIdx.y * CHUNK;
    tb = max(tb, c0);
    te = min(te, min(c0 + CHUNK - 1, ND - 1));
    if (tb > te) return;   // wave-uniform (window depends only on n,j)

    const float scale = 1.4979898876271372f;   // 2*me/222
    float result;

    if (rz == 0.0f) {
        // z fixed for whole ray: hoist all z math.
        const float z0f = floorf(bz);
        const float fz = bz - z0f;
        const int z0 = (int)z0f, z1 = z0 + 1;
        const float wz0 = ((unsigned)z0 < 128u) ? (1.0f - fz) : 0.0f;
        const float wz1 = ((unsigned)z1 < 128u) ? fz : 0.0f;
        const int za = min(max(z0, 0), 127);
        const int zb = min(max(z1, 0), 127);

        if (wz1 == 0.0f) {
            // fast path (this input: fz==0 exactly): 4 loads / iter
            float acc = 0.0f;
            #pragma unroll 2
            for (int t = tb; t <= te; ++t) {
                const float tc = fmaf(dtc, (float)t, t0c);
                const float ix = fmaf(tc, rx, bx);
                const float iy = fmaf(tc, ry, by);
                const float x0f = floorf(ix), y0f = floorf(iy);
                const float fx = ix - x0f, fy = iy - y0f;
                const int x0 = (int)x0f, y0 = (int)y0f;
                const float wx0 = ((unsigned)x0 < 128u) ? (1.0f - fx) : 0.0f;
                const float wx1 = ((unsigned)(x0 + 1) < 128u) ? fx : 0.0f;
                const float wy0 = ((unsigned)y0 < 128u) ? (1.0f - fy) : 0.0f;
                const float wy1 = ((unsigned)(y0 + 1) < 128u) ? fy : 0.0f;
                const int xa = min(max(x0, 0), 127) << 14;
                const int xb = min(max(x0 + 1, 0), 127) << 14;
                const int ya = min(max(y0, 0), 127) << 7;
                const int yb = min(max(y0 + 1, 0), 127) << 7;
                float s = wx0 * wy0 * vol[xa + ya + za];
                s = fmaf(wx0 * wy1, vol[xa + yb + za], s);
                s = fmaf(wx1 * wy0, vol[xb + ya + za], s);
                s = fmaf(wx1 * wy1, vol[xb + yb + za], s);
                acc += s;
            }
            result = acc * wz0 * scale;
        } else {
            // z-interp but z-invariant: 8 loads, z weights hoisted
            float acc = 0.0f;
            for (int t = tb; t <= te; ++t) {
                const float tc = fmaf(dtc, (float)t, t0c);
                const float ix = fmaf(tc, rx, bx);
                const float iy = fmaf(tc, ry, by);
                const float x0f = floorf(ix), y0f = floorf(iy);
                const float fx = ix - x0f, fy = iy - y0f;
                const int x0 = (int)x0f, y0 = (int)y0f;
                const float wx0 = ((unsigned)x0 < 128u) ? (1.0f - fx) : 0.0f;
                const float wx1 = ((unsigned)(x0 + 1) < 128u) ? fx : 0.0f;
                const float wy0 = ((unsigned)y0 < 128u) ? (1.0f - fy) : 0.0f;
                const float wy1 = ((unsigned)(y0 + 1) < 128u) ? fy : 0.0f;
                const int xa = min(max(x0, 0), 127) << 14;
                const int xb = min(max(x0 + 1, 0), 127) << 14;
                const int ya = min(max(y0, 0), 127) << 7;
                const int yb = min(max(y0 + 1, 0), 127) << 7;
                const float w00 = wx0 * wy0, w01 = wx0 * wy1;
                const float w10 = wx1 * wy0, w11 = wx1 * wy1;
                float s0 = w00 * vol[xa + ya + za];
                s0 = fmaf(w01, vol[xa + yb + za], s0);
                s0 = fmaf(w10, vol[xb + ya + za], s0);
                s0 = fmaf(w11, vol[xb + yb + za], s0);
                float s1 = w00 * vol[xa + ya + zb];
                s1 = fmaf(w01, vol[xa + yb + zb], s1);
                s1 = fmaf(w10, vol[xb + ya + zb], s1);
                s1 = fmaf(w11, vol[xb + yb + zb], s1);
                acc = fmaf(s0, wz0, acc);
                acc = fmaf(s1, wz1, acc);
            }
            result = acc * scale;
        }
    } else {
        // fully general path (unused for this input)
        float acc = 0.0f;
        for (int t = tb; t <= te; ++t) {
            const float tc = fmaf(dtc, (float)t, t0c);
            const float ix = fmaf(tc, rx, bx);
            const float iy = fmaf(tc, ry, by);
            const float iz = fmaf(tc, rz, bz);
            const float x0f = floorf(ix), y0f = floorf(iy), z0f = floorf(iz);
            const float fx = ix - x0f, fy = iy - y0f, fz = iz - z0f;
            const int x0 = (int)x0f, y0 = (int)y0f, z0 = (int)z0f;
            const float wx0 = ((unsigned)x0 < 128u) ? (1.0f - fx) : 0.0f;
            const float wx1 = ((unsigned)(x0 + 1) < 128u) ? fx : 0.0f;
            const float wy0 = ((unsigned)y0 < 128u) ? (1.0f - fy) : 0.0f;
            const float wy1 = ((unsigned)(y0 + 1) < 128u) ? fy : 0.0f;
            const float wz0 = ((unsigned)z0 < 128u) ? (1.0f - fz) : 0.0f;
            const float wz1 = ((unsigned)(z0 + 1) < 128u) ? fz : 0.0f;
            const int xa = min(max(x0, 0), 127) << 14;
            const int xb = min(max(x0 + 1, 0), 127) << 14;
            const int ya = min(max(y0, 0), 127) << 7;
            const int yb = min(max(y0 + 1, 0), 127) << 7;
            const int za = min(max(z0, 0), 127);
            const int zb = min(max(z0 + 1, 0), 127);
            const float w00 = wx0 * wy0, w01 = wx0 * wy1;
            const float w10 = wx1 * wy0, w11 = wx1 * wy1;
            float s0 = w00 * vol[xa + ya + za];
            s0 = fmaf(w01, vol[xa + yb + za], s0);
            s0 = fmaf(w10, vol[xb + ya + za], s0);
            s0 = fmaf(w11, vol[xb + yb + za], s0);
            float s1 = w00 * vol[xa + ya + zb];
            s1 = fmaf(w01, vol[xa + yb + zb], s1);
            s1 = fmaf(w10, vol[xb + ya + zb], s1);
            s1 = fmaf(w11, vol[xb + yb + zb], s1);
            acc = fmaf(s0, wz0, acc);
            acc = fmaf(s1, wz1, acc);
        }
        result = acc * scale;
    }

    atomicAdd(out + tid, result);
}

extern "C" void kernel_launch(void* const* d_in, const int* in_sizes, int n_in,
                              void* d_out, int out_size, void* d_ws, size_t ws_size,
                              hipStream_t stream) {
    const float* vol  = (const float*)d_in[0];   // (128,128,128) fp32
    const float* vecs = (const float*)d_in[1];   // (8,12) fp32
    float* out = (float*)d_out;                  // (8,128,128) fp32

    hipMemsetAsync(out, 0, (size_t)out_size * sizeof(float), stream);

    const int total = 8 * 128 * 128;             // == out_size
    dim3 block(256);
    dim3 grid(total / 256, NCHUNK);
    projector_kernel<<<grid, block, 0, stream>>>(vol, vecs, out);
}

// Round 3
// 75.259 us; speedup vs baseline: 1.4034x; 1.0451x over previous
//
#include <hip/hip_runtime.h>

// Projector: out[n][j][k] = scale * sum_t trilinear(vol, p(t)+63.5)
//   p(t) = dc + j_c[j]*u + k_c[k]*v + t_c[t]*ray,  j_c/k_c = idx-63.5
// Constants (X=Y=Z=128): n_depth=222, max_extent=96*sqrt(3), dt=2*me/221,
// scale=2*me/222.
//
// R3: one block per (n,j) row, block=512 = 4 t-quarters x 128 k.
//  - degenerate-z fast path (this input: rz=uz=dcz=0, v=(0,0,1) => iz==k
//    exactly): weight math depends only on blockIdx+loop var (wave-uniform,
//    scalarizable), loads are rowbase + k*4 (perfectly coalesced).
//  - t-window quartered across th -> LDS reduce -> single coalesced store.
//    No atomics, no output memset. grid 1024 x 8 waves = 32 waves/CU exact.
constexpr int ND = 222;

__global__ __launch_bounds__(512) void projector_kernel(
    const float* __restrict__ vol,
    const float* __restrict__ vecs,
    float* __restrict__ out)
{
    const int rowid = blockIdx.x;          // n*128 + j
    const int n = rowid >> 7;
    const int j = rowid & 127;
    const int k = threadIdx.x & 127;
    const int th = threadIdx.x >> 7;       // t-quarter 0..3

    const float* vp = vecs + n * 12;
    const float rx = vp[0], ry = vp[1], rz = vp[2];
    const float dcx = vp[3], dcy = vp[4], dcz = vp[5];
    const float ux = vp[6], uy = vp[7], uz = vp[8];
    const float vx = vp[9], vy = vp[10], vz = vp[11];

    const float jc = (float)j - 63.5f;
    const float kc = (float)k - 63.5f;

    const float t0c = -166.2768775266122f;   // -max_extent
    const float dtc = 1.5047681223222824f;   // 2*me/221
    const float scale = 1.4979898876271372f; // 2*me/222

    __shared__ float part[4][128];

    const bool degen = (rz == 0.0f) & (uz == 0.0f) & (dcz == 0.0f) &
                       (vx == 0.0f) & (vy == 0.0f) & (vz == 1.0f);

    float acc = 0.0f;

    if (degen) {
        // Row-uniform 2D problem in x-y; z slice == k exactly (fz==0).
        const float bx = dcx + jc * ux + 63.5f;
        const float by = dcy + jc * uy + 63.5f;

        // analytic t-window from x,y slabs (z never constrains: iz=k in-range)
        float tlo = -1e30f, thi = 1e30f;
        const float bsv[2] = {bx, by};
        const float rsv[2] = {rx, ry};
        #pragma unroll
        for (int a = 0; a < 2; ++a) {
            const float b = bsv[a], r = rsv[a];
            if (fabsf(r) > 1e-8f) {
                const float inv = 1.0f / r;
                const float t1 = (-1.01f - b) * inv;
                const float t2 = (128.01f - b) * inv;
                tlo = fmaxf(tlo, fminf(t1, t2));
                thi = fminf(thi, fmaxf(t1, t2));
            } else if (b < -1.01f || b > 128.01f) {
                tlo = 1e30f; thi = -1e30f;
            }
        }
        int tb = (int)ceilf((tlo - t0c) / dtc);
        int te = (int)floorf((thi - t0c) / dtc);
        tb = max(tb, 0); te = min(te, ND - 1);

        // quarter the (block-uniform) window among th
        const int len = max(te - tb + 1, 0);
        const int q = (len + 3) >> 2;
        const int mtb = tb + th * q;
        const int mte = min(mtb + q - 1, te);

        #pragma unroll 4
        for (int t = mtb; t <= mte; ++t) {
            const float tc = fmaf(dtc, (float)t, t0c);
            const float ix = fmaf(tc, rx, bx);
            const float iy = fmaf(tc, ry, by);
            const float x0f = floorf(ix), y0f = floorf(iy);
            const float fx = ix - x0f, fy = iy - y0f;
            const int x0 = (int)x0f, y0 = (int)y0f;
            const float wx0 = ((unsigned)x0 < 128u) ? (1.0f - fx) : 0.0f;
            const float wx1 = ((unsigned)(x0 + 1) < 128u) ? fx : 0.0f;
            const float wy0 = ((unsigned)y0 < 128u) ? (1.0f - fy) : 0.0f;
            const float wy1 = ((unsigned)(y0 + 1) < 128u) ? fy : 0.0f;
            const int xa = min(max(x0, 0), 127) << 14;
            const int xb = min(max(x0 + 1, 0), 127) << 14;
            const int ya = min(max(y0, 0), 127) << 7;
            const int yb = min(max(y0 + 1, 0), 127) << 7;
            float s = wx0 * wy0 * vol[xa + ya + k];
            s = fmaf(wx0 * wy1, vol[xa + yb + k], s);
            s = fmaf(wx1 * wy0, vol[xb + ya + k], s);
            s = fmaf(wx1 * wy1, vol[xb + yb + k], s);
            acc += s;
        }
    } else {
        // General per-lane path (unused for this input): fixed quarter of
        // [0,ND) intersected with the per-lane analytic window.
        const float bx = dcx + jc * ux + kc * vx + 63.5f;
        const float by = dcy + jc * uy + kc * vy + 63.5f;
        const float bz = dcz + jc * uz + kc * vz + 63.5f;

        float tlo = -1e30f, thi = 1e30f;
        const float bsv[3] = {bx, by, bz};
        const float rsv[3] = {rx, ry, rz};
        #pragma unroll
        for (int a = 0; a < 3; ++a) {
            const float b = bsv[a], r = rsv[a];
            if (fabsf(r) > 1e-8f) {
                const float inv = 1.0f / r;
                const float t1 = (-1.01f - b) * inv;
                const float t2 = (128.01f - b) * inv;
                tlo = fmaxf(tlo, fminf(t1, t2));
                thi = fminf(thi, fmaxf(t1, t2));
            } else if (b < -1.01f || b > 128.01f) {
                tlo = 1e30f; thi = -1e30f;
            }
        }
        int tb = (int)ceilf((tlo - t0c) / dtc);
        int te = (int)floorf((thi - t0c) / dtc);
        const int q = (ND + 3) >> 2;           // 56
        tb = max(tb, th * q);
        te = min(te, min(th * q + q - 1, ND - 1));

        for (int t = tb; t <= te; ++t) {
            const float tc = fmaf(dtc, (float)t, t0c);
            const float ix = fmaf(tc, rx, bx);
            const float iy = fmaf(tc, ry, by);
            const float iz = fmaf(tc, rz, bz);
            const float x0f = floorf(ix), y0f = floorf(iy), z0f = floorf(iz);
            const float fx = ix - x0f, fy = iy - y0f, fz = iz - z0f;
            const int x0 = (int)x0f, y0 = (int)y0f, z0 = (int)z0f;
            const float wx0 = ((unsigned)x0 < 128u) ? (1.0f - fx) : 0.0f;
            const float wx1 = ((unsigned)(x0 + 1) < 128u) ? fx : 0.0f;
            const float wy0 = ((unsigned)y0 < 128u) ? (1.0f - fy) : 0.0f;
            const float wy1 = ((unsigned)(y0 + 1) < 128u) ? fy : 0.0f;
            const float wz0 = ((unsigned)z0 < 128u) ? (1.0f - fz) : 0.0f;
            const float wz1 = ((unsigned)(z0 + 1) < 128u) ? fz : 0.0f;
            const int xa = min(max(x0, 0), 127) << 14;
            const int xb = min(max(x0 + 1, 0), 127) << 14;
            const int ya = min(max(y0, 0), 127) << 7;
            const int yb = min(max(y0 + 1, 0), 127) << 7;
            const int za = min(max(z0, 0), 127);
            const int zb = min(max(z0 + 1, 0), 127);
            const float w00 = wx0 * wy0, w01 = wx0 * wy1;
            const float w10 = wx1 * wy0, w11 = wx1 * wy1;
            float s0 = w00 * vol[xa + ya + za];
            s0 = fmaf(w01, vol[xa + yb + za], s0);
            s0 = fmaf(w10, vol[xb + ya + za], s0);
            s0 = fmaf(w11, vol[xb + yb + za], s0);
            float s1 = w00 * vol[xa + ya + zb];
            s1 = fmaf(w01, vol[xa + yb + zb], s1);
            s1 = fmaf(w10, vol[xb + ya + zb], s1);
            s1 = fmaf(w11, vol[xb + yb + zb], s1);
            acc = fmaf(s0, wz0, acc);
            acc = fmaf(s1, wz1, acc);
        }
    }

    // reduce the 4 t-quarters (stride-1 LDS: conflict-free)
    if (th != 0) part[th][k] = acc;
    __syncthreads();
    if (th == 0) {
        const float s = acc + part[1][k] + part[2][k] + part[3][k];
        out[rowid * 128 + k] = s * scale;
    }
}

extern "C" void kernel_launch(void* const* d_in, const int* in_sizes, int n_in,
                              void* d_out, int out_size, void* d_ws, size_t ws_size,
                              hipStream_t stream) {
    const float* vol  = (const float*)d_in[0];   // (128,128,128) fp32
    const float* vecs = (const float*)d_in[1];   // (8,12) fp32
    float* out = (float*)d_out;                  // (8,128,128) fp32

    dim3 block(512);
    dim3 grid(8 * 128);                          // one block per (n,j) row
    projector_kernel<<<grid, block, 0, stream>>>(vol, vecs, out);
}